// Round 10
// baseline (36.070 us; speedup 1.0000x reference)
//
#include <hip/hip_runtime.h>
#include <math.h>

// Problem constants (from reference setup_inputs): z_list (P,B,D) fp32
constexpr int P = 64, B = 512, D = 1024;
constexpr int D4 = D / 4;           // 256 float4 per row
constexpr int WAVES = 8;            // waves per block in main kernel (512 thr)
constexpr int PC = P / WAVES;       // 8 p-rows per wave (4 pairs)
constexpr int TB = 32;              // tail blocks (d-split: 8 float4 cols each)
#define EPS 1e-8f

__device__ inline float wave_reduce_sum(float v) {
#pragma unroll
  for (int off = 1; off < 64; off <<= 1) v += __shfl_xor(v, off);
  return v;
}

__device__ inline float dot4(const float4& a, const float4& b) {
  return a.x * b.x + a.y * b.y + a.z * b.z + a.w * b.w;
}

// K_main: one block (8 waves, 512 thr) per b -> 16 waves/CU (2 blocks/CU,
// LDS-limited at 64 KB). Each wave streams 8 p-rows of z[:,b,:] as 4
// row-pairs (depth-1 prefetch, 2 interleaved norm-reduce chains). LDS
// combines the 8 waves; block normalizes mean row -> an[b], writes Uv[b],
// diag[b] = Uv.an. Block 0 zeroes out[0] (tail accumulates into it).
// R7 measured the 4-wave variant at 27.3 us (~4.8 TB/s); this doubles
// waves/CU with everything else identical.
__global__ __launch_bounds__(512) void k_main(const float* __restrict__ z,
                                              float* __restrict__ an,
                                              float* __restrict__ Uv,
                                              float* __restrict__ diag,
                                              float* __restrict__ out) {
  const int b = blockIdx.x;
  const int t = threadIdx.x;
  const int w = t >> 6;              // wave 0..7
  const int lane = t & 63;

  if (b == 0 && t == 0) out[0] = 0.f;  // boundary-visible to k_tail

  __shared__ float4 lds_zs[WAVES][D4];  // 32 KB
  __shared__ float4 lds_uu[WAVES][D4];  // 32 KB
  __shared__ float red[8];

  float4 zs[4], uu[4];
#pragma unroll
  for (int k = 0; k < 4; ++k) {
    zs[k] = make_float4(0.f, 0.f, 0.f, 0.f);
    uu[k] = make_float4(0.f, 0.f, 0.f, 0.f);
  }

  // wave w handles p = w*PC .. w*PC+PC-1, rows z[p][b][:]
  const size_t pstride = (size_t)B * D4;  // float4 stride between p's
  const float4* base = (const float4*)z + ((size_t)(w * PC) * B + b) * D4;

  float4 curA[4], curB[4];
#pragma unroll
  for (int k = 0; k < 4; ++k) {
    curA[k] = base[k * 64 + lane];
    curB[k] = base[pstride + k * 64 + lane];
  }

  for (int pr = 0; pr < PC / 2; ++pr) {
    float4 nxtA[4], nxtB[4];
    const bool more = (pr + 1 < PC / 2);
    if (more) {
      const float4* nA = base + (size_t)(2 * pr + 2) * pstride;
      const float4* nB = base + (size_t)(2 * pr + 3) * pstride;
#pragma unroll
      for (int k = 0; k < 4; ++k) {
        nxtA[k] = nA[k * 64 + lane];
        nxtB[k] = nB[k * 64 + lane];
      }
    }

    // two independent norm reductions, interleaved for ILP
    float ssA = 0.f, ssB = 0.f;
#pragma unroll
    for (int k = 0; k < 4; ++k) {
      ssA += dot4(curA[k], curA[k]);
      ssB += dot4(curB[k], curB[k]);
    }
#pragma unroll
    for (int off = 1; off < 64; off <<= 1) {
      ssA += __shfl_xor(ssA, off);
      ssB += __shfl_xor(ssB, off);
    }
    const float wA = 1.0f / fmaxf(sqrtf(ssA), EPS);
    const float wB = 1.0f / fmaxf(sqrtf(ssB), EPS);

#pragma unroll
    for (int k = 0; k < 4; ++k) {
      zs[k].x += curA[k].x + curB[k].x;
      zs[k].y += curA[k].y + curB[k].y;
      zs[k].z += curA[k].z + curB[k].z;
      zs[k].w += curA[k].w + curB[k].w;
      uu[k].x += wA * curA[k].x + wB * curB[k].x;
      uu[k].y += wA * curA[k].y + wB * curB[k].y;
      uu[k].z += wA * curA[k].z + wB * curB[k].z;
      uu[k].w += wA * curA[k].w + wB * curB[k].w;
    }
    if (more) {
#pragma unroll
      for (int k = 0; k < 4; ++k) {
        curA[k] = nxtA[k];
        curB[k] = nxtB[k];
      }
    }
  }

  // cross-wave combine: wave w's float4 index k*64+lane
#pragma unroll
  for (int k = 0; k < 4; ++k) {
    lds_zs[w][k * 64 + lane] = zs[k];
    lds_uu[w][k * 64 + lane] = uu[k];
  }
  __syncthreads();

  // threads 0..255: thread t owns float4 index t (d = 4t..4t+3)
  float4 zsum = make_float4(0.f, 0.f, 0.f, 0.f);
  float4 usum = make_float4(0.f, 0.f, 0.f, 0.f);
  if (t < 256) {
#pragma unroll
    for (int ww = 0; ww < WAVES; ++ww) {
      float4 a = lds_zs[ww][t];
      float4 u = lds_uu[ww][t];
      zsum.x += a.x; zsum.y += a.y; zsum.z += a.z; zsum.w += a.w;
      usum.x += u.x; usum.y += u.y; usum.z += u.z; usum.w += u.w;
    }
    float ssq = wave_reduce_sum(dot4(zsum, zsum));
    if (lane == 0) red[w] = ssq;  // w in 0..3 here
  }
  __syncthreads();
  if (t < 256) {
    const float ss2 = red[0] + red[1] + red[2] + red[3];
    // an = (z_sum/P)/max(||z_sum||/P, eps) = z_sum / max(||z_sum||, P*eps)
    const float inv = 1.0f / fmaxf(sqrtf(ss2), (float)P * EPS);
    float4 a4 = make_float4(zsum.x * inv, zsum.y * inv, zsum.z * inv, zsum.w * inv);

    ((float4*)an)[(size_t)b * D4 + t] = a4;
    ((float4*)Uv)[(size_t)b * D4 + t] = usum;

    float dg = wave_reduce_sum(dot4(usum, a4));
    if (lane == 0) red[4 + w] = dg;
  }
  __syncthreads();
  if (t == 0) diag[b] = red[4] + red[5] + red[6] + red[7];
}

// K_tail: 32 blocks, d-split. Block blk owns float4-columns [blk*8, blk*8+8)
// (32 scalar cols). Thread t: f4col = t&7, rowgroup = t>>3; accumulates
// S4/T4 over rows r = rowgroup + 32*i. Wave shfl (offsets 8/16/32) + LDS
// combine complete the column sums; threads 0..7 dot them; block adds ONE
// scalar to out[0] (33 total adds -> no contention; R5/R8 lesson applied).
__global__ __launch_bounds__(256) void k_tail(const float* __restrict__ an,
                                              const float* __restrict__ Uv,
                                              const float* __restrict__ diag,
                                              float* __restrict__ out) {
  const int blk = blockIdx.x;
  const int t = threadIdx.x;
  const int w = t >> 6;
  const int lane = t & 63;
  const int f4c = blk * 8 + (t & 7);   // this thread's float4 column
  const int rg = t >> 3;               // rowgroup 0..31

  float4 S = make_float4(0.f, 0.f, 0.f, 0.f);
  float4 T = make_float4(0.f, 0.f, 0.f, 0.f);
#pragma unroll 4
  for (int i = 0; i < 16; ++i) {
    const size_t r = (size_t)rg + 32 * i;   // rows rg, rg+32, ..., rg+480
    float4 a = ((const float4*)an)[r * D4 + f4c];
    float4 u = ((const float4*)Uv)[r * D4 + f4c];
    S.x += a.x; S.y += a.y; S.z += a.z; S.w += a.w;
    T.x += u.x; T.y += u.y; T.z += u.z; T.w += u.w;
  }

  // reduce over the 8 rowgroups within this wave (lanes sharing lane&7)
#pragma unroll
  for (int off = 8; off < 64; off <<= 1) {
    S.x += __shfl_xor(S.x, off); S.y += __shfl_xor(S.y, off);
    S.z += __shfl_xor(S.z, off); S.w += __shfl_xor(S.w, off);
    T.x += __shfl_xor(T.x, off); T.y += __shfl_xor(T.y, off);
    T.z += __shfl_xor(T.z, off); T.w += __shfl_xor(T.w, off);
  }

  // combine the 4 waves via LDS
  __shared__ float4 ldsS[4][8], ldsT[4][8];
  if (lane < 8) {
    ldsS[w][lane] = S;
    ldsT[w][lane] = T;
  }
  __syncthreads();

  float dotp = 0.f;
  if (t < 8) {
    float4 Sf = ldsS[0][t], Tf = ldsT[0][t];
#pragma unroll
    for (int ww = 1; ww < 4; ++ww) {
      float4 s2 = ldsS[ww][t], t2 = ldsT[ww][t];
      Sf.x += s2.x; Sf.y += s2.y; Sf.z += s2.z; Sf.w += s2.w;
      Tf.x += t2.x; Tf.y += t2.y; Tf.z += t2.z; Tf.w += t2.w;
    }
    dotp = dot4(Sf, Tf);
  }
  // diag slice: 16 b's per block, lanes 16..31 of wave 0
  float dgp = 0.f;
  if (t >= 16 && t < 32) dgp = diag[blk * 16 + (t - 16)];

  if (w == 0) {
    float v = dotp - dgp;
    // sum lanes 0..31 (dot in 0..7, diag in 16..31): offsets 1,2,4,8,16
#pragma unroll
    for (int off = 1; off < 32; off <<= 1) v += __shfl_xor(v, off);
    if (t == 0) {
      const float count = 64.0f * 512.0f * 511.0f;  // P*B*(B-1)
      float contrib = v / count + (blk == 0 ? -1.0f : 0.0f);
      atomicAdd(out, contrib);
    }
  }
}

extern "C" void kernel_launch(void* const* d_in, const int* in_sizes, int n_in,
                              void* d_out, int out_size, void* d_ws, size_t ws_size,
                              hipStream_t stream) {
  const float* z = (const float*)d_in[0];  // z_list (P,B,D); d_in[1] unused

  float* ws = (float*)d_ws;
  float* an = ws;                                  // B*D (2 MB)
  float* Uv = an + (size_t)B * D;                  // B*D (2 MB)
  float* diag = Uv + (size_t)B * D;                // B

  k_main<<<B, 512, 0, stream>>>(z, an, Uv, diag, (float*)d_out);
  k_tail<<<TB, 256, 0, stream>>>(an, Uv, diag, (float*)d_out);
}

// Round 11
// 32.877 us; speedup vs baseline: 1.0971x; 1.0971x over previous
//
#include <hip/hip_runtime.h>
#include <math.h>

// Problem constants (from reference setup_inputs): z_list (P,B,D) fp32
constexpr int P = 64, B = 512, D = 1024;
constexpr int D4 = D / 4;           // 256 float4 per row
constexpr int WAVES = 4;            // waves per block in main kernel
constexpr int PC = P / WAVES;       // 16 p's per wave
constexpr int TB = 32;              // tail blocks (d-split: 8 float4 cols each)
#define EPS 1e-8f

__device__ inline float wave_reduce_sum(float v) {
#pragma unroll
  for (int off = 1; off < 64; off <<= 1) v += __shfl_xor(v, off);
  return v;
}

__device__ inline float dot4(const float4& a, const float4& b) {
  return a.x * b.x + a.y * b.y + a.z * b.z + a.w * b.w;
}

// K_main: one block (4 waves) per PAIR of adjacent b's (b0=2*blk, b1=b0+1).
// z[p][b0][:] and z[p][b1][:] are contiguous -> each wave's load step is one
// 8 KB CONTIGUOUS chunk (vs 2x scattered 4 KB in R9): half the stream count
// (1024 waves, 4 waves/CU), double the per-request spatial granularity.
// Per p: load both rows (cur[0..3]=b0, cur[4..7]=b1), two independent
// norm-reduce chains, accumulate zs/uu per b. Depth-1 prefetch of next p.
// Epilogue runs twice (b0, b1) reusing the same LDS. Block 0 zeroes out[0].
__global__ __launch_bounds__(256) void k_main(const float* __restrict__ z,
                                              float* __restrict__ an,
                                              float* __restrict__ Uv,
                                              float* __restrict__ diag,
                                              float* __restrict__ out) {
  const int blk = blockIdx.x;
  const int b0 = blk * 2;
  const int t = threadIdx.x;
  const int w = t >> 6;              // wave 0..3
  const int lane = t & 63;

  if (blk == 0 && t == 0) out[0] = 0.f;  // boundary-visible to k_tail

  __shared__ float4 lds_zs[WAVES][D4];  // 16 KB (reused for b0 then b1)
  __shared__ float4 lds_uu[WAVES][D4];  // 16 KB
  __shared__ float red[2 * WAVES];

  // accumulators: [bb][k]
  float4 zs0[4], uu0[4], zs1[4], uu1[4];
#pragma unroll
  for (int k = 0; k < 4; ++k) {
    zs0[k] = make_float4(0.f, 0.f, 0.f, 0.f);
    uu0[k] = make_float4(0.f, 0.f, 0.f, 0.f);
    zs1[k] = make_float4(0.f, 0.f, 0.f, 0.f);
    uu1[k] = make_float4(0.f, 0.f, 0.f, 0.f);
  }

  // wave w handles p = w*PC .. w*PC+PC-1; per p reads the contiguous pair
  // z[p][b0][:] ++ z[p][b1][:] = 512 float4 = 8 float4 per lane (k*64+lane)
  const size_t pstride = (size_t)B * D4;  // float4 stride between p's
  const float4* base = (const float4*)z + ((size_t)(w * PC) * B + b0) * D4;

  float4 cur[8], nxt[8];
#pragma unroll
  for (int k = 0; k < 8; ++k) cur[k] = base[k * 64 + lane];

  for (int pp = 0; pp < PC; ++pp) {
    const bool more = (pp + 1 < PC);
    if (more) {
      const float4* nb = base + (size_t)(pp + 1) * pstride;
#pragma unroll
      for (int k = 0; k < 8; ++k) nxt[k] = nb[k * 64 + lane];
    }

    // two independent norm reductions (row b0: cur[0..3], row b1: cur[4..7])
    float ssA = 0.f, ssB = 0.f;
#pragma unroll
    for (int k = 0; k < 4; ++k) {
      ssA += dot4(cur[k], cur[k]);
      ssB += dot4(cur[4 + k], cur[4 + k]);
    }
#pragma unroll
    for (int off = 1; off < 64; off <<= 1) {
      ssA += __shfl_xor(ssA, off);
      ssB += __shfl_xor(ssB, off);
    }
    const float wA = 1.0f / fmaxf(sqrtf(ssA), EPS);
    const float wB = 1.0f / fmaxf(sqrtf(ssB), EPS);

#pragma unroll
    for (int k = 0; k < 4; ++k) {
      const float4 a = cur[k], c = cur[4 + k];
      zs0[k].x += a.x; zs0[k].y += a.y; zs0[k].z += a.z; zs0[k].w += a.w;
      uu0[k].x += wA * a.x; uu0[k].y += wA * a.y;
      uu0[k].z += wA * a.z; uu0[k].w += wA * a.w;
      zs1[k].x += c.x; zs1[k].y += c.y; zs1[k].z += c.z; zs1[k].w += c.w;
      uu1[k].x += wB * c.x; uu1[k].y += wB * c.y;
      uu1[k].z += wB * c.z; uu1[k].w += wB * c.w;
    }
    if (more) {
#pragma unroll
      for (int k = 0; k < 8; ++k) cur[k] = nxt[k];
    }
  }

  // epilogue per b (reuse LDS): combine 4 waves, normalize, store, diag
#pragma unroll
  for (int bb = 0; bb < 2; ++bb) {
    const int b = b0 + bb;
#pragma unroll
    for (int k = 0; k < 4; ++k) {
      lds_zs[w][k * 64 + lane] = bb ? zs1[k] : zs0[k];
      lds_uu[w][k * 64 + lane] = bb ? uu1[k] : uu0[k];
    }
    __syncthreads();

    // thread t owns float4 index t (d = 4t..4t+3)
    float4 zsum = make_float4(0.f, 0.f, 0.f, 0.f);
    float4 usum = make_float4(0.f, 0.f, 0.f, 0.f);
#pragma unroll
    for (int ww = 0; ww < WAVES; ++ww) {
      float4 a = lds_zs[ww][t];
      float4 u = lds_uu[ww][t];
      zsum.x += a.x; zsum.y += a.y; zsum.z += a.z; zsum.w += a.w;
      usum.x += u.x; usum.y += u.y; usum.z += u.z; usum.w += u.w;
    }

    float ss = wave_reduce_sum(dot4(zsum, zsum));
    if (lane == 0) red[w] = ss;
    __syncthreads();
    ss = red[0] + red[1] + red[2] + red[3];

    // an = (z_sum/P)/max(||z_sum||/P, eps) = z_sum / max(||z_sum||, P*eps)
    const float inv = 1.0f / fmaxf(sqrtf(ss), (float)P * EPS);
    float4 a4 = make_float4(zsum.x * inv, zsum.y * inv, zsum.z * inv, zsum.w * inv);

    ((float4*)an)[(size_t)b * D4 + t] = a4;
    ((float4*)Uv)[(size_t)b * D4 + t] = usum;

    float dg = wave_reduce_sum(dot4(usum, a4));
    if (lane == 0) red[WAVES + w] = dg;
    __syncthreads();
    if (t == 0) diag[b] = red[WAVES] + red[WAVES + 1] + red[WAVES + 2] + red[WAVES + 3];
    __syncthreads();  // protect LDS reuse for next bb
  }
}

// K_tail: 32 blocks, d-split. Block blk owns float4-columns [blk*8, blk*8+8)
// (32 scalar cols). Thread t: f4col = t&7, rowgroup = t>>3; accumulates
// S4/T4 over rows r = rowgroup + 32*i. Wave shfl (offsets 8/16/32) + LDS
// combine complete the column sums; threads 0..7 dot them; block adds ONE
// scalar to out[0] (33 total adds -> no contention; R5/R8 lesson applied).
__global__ __launch_bounds__(256) void k_tail(const float* __restrict__ an,
                                              const float* __restrict__ Uv,
                                              const float* __restrict__ diag,
                                              float* __restrict__ out) {
  const int blk = blockIdx.x;
  const int t = threadIdx.x;
  const int w = t >> 6;
  const int lane = t & 63;
  const int f4c = blk * 8 + (t & 7);   // this thread's float4 column
  const int rg = t >> 3;               // rowgroup 0..31

  float4 S = make_float4(0.f, 0.f, 0.f, 0.f);
  float4 T = make_float4(0.f, 0.f, 0.f, 0.f);
#pragma unroll 4
  for (int i = 0; i < 16; ++i) {
    const size_t r = (size_t)rg + 32 * i;   // rows rg, rg+32, ..., rg+480
    float4 a = ((const float4*)an)[r * D4 + f4c];
    float4 u = ((const float4*)Uv)[r * D4 + f4c];
    S.x += a.x; S.y += a.y; S.z += a.z; S.w += a.w;
    T.x += u.x; T.y += u.y; T.z += u.z; T.w += u.w;
  }

  // reduce over the 8 rowgroups within this wave (lanes sharing lane&7)
#pragma unroll
  for (int off = 8; off < 64; off <<= 1) {
    S.x += __shfl_xor(S.x, off); S.y += __shfl_xor(S.y, off);
    S.z += __shfl_xor(S.z, off); S.w += __shfl_xor(S.w, off);
    T.x += __shfl_xor(T.x, off); T.y += __shfl_xor(T.y, off);
    T.z += __shfl_xor(T.z, off); T.w += __shfl_xor(T.w, off);
  }

  // combine the 4 waves via LDS
  __shared__ float4 ldsS[4][8], ldsT[4][8];
  if (lane < 8) {
    ldsS[w][lane] = S;
    ldsT[w][lane] = T;
  }
  __syncthreads();

  float dotp = 0.f;
  if (t < 8) {
    float4 Sf = ldsS[0][t], Tf = ldsT[0][t];
#pragma unroll
    for (int ww = 1; ww < 4; ++ww) {
      float4 s2 = ldsS[ww][t], t2 = ldsT[ww][t];
      Sf.x += s2.x; Sf.y += s2.y; Sf.z += s2.z; Sf.w += s2.w;
      Tf.x += t2.x; Tf.y += t2.y; Tf.z += t2.z; Tf.w += t2.w;
    }
    dotp = dot4(Sf, Tf);
  }
  // diag slice: 16 b's per block, lanes 16..31 of wave 0
  float dgp = 0.f;
  if (t >= 16 && t < 32) dgp = diag[blk * 16 + (t - 16)];

  if (w == 0) {
    float v = dotp - dgp;
    // sum lanes 0..31 (dot in 0..7, diag in 16..31): offsets 1,2,4,8,16
#pragma unroll
    for (int off = 1; off < 32; off <<= 1) v += __shfl_xor(v, off);
    if (t == 0) {
      const float count = 64.0f * 512.0f * 511.0f;  // P*B*(B-1)
      float contrib = v / count + (blk == 0 ? -1.0f : 0.0f);
      atomicAdd(out, contrib);
    }
  }
}

extern "C" void kernel_launch(void* const* d_in, const int* in_sizes, int n_in,
                              void* d_out, int out_size, void* d_ws, size_t ws_size,
                              hipStream_t stream) {
  const float* z = (const float*)d_in[0];  // z_list (P,B,D); d_in[1] unused

  float* ws = (float*)d_ws;
  float* an = ws;                                  // B*D (2 MB)
  float* Uv = an + (size_t)B * D;                  // B*D (2 MB)
  float* diag = Uv + (size_t)B * D;                // B

  k_main<<<B / 2, 256, 0, stream>>>(z, an, Uv, diag, (float*)d_out);
  k_tail<<<TB, 256, 0, stream>>>(an, Uv, diag, (float*)d_out);
}

// Round 13
// 31.845 us; speedup vs baseline: 1.1327x; 1.0324x over previous
//
#include <hip/hip_runtime.h>
#include <math.h>

// Problem constants (from reference setup_inputs): z_list (P,B,D) fp32
constexpr int P = 64, B = 512, D = 1024;
constexpr int D4 = D / 4;           // 256 float4 per row
constexpr int WAVES = 4;            // waves per block in main kernel
constexpr int PC = P / WAVES;       // 16 p-rows per wave (8 pairs)
constexpr int TB = 32;              // tail blocks (d-split: 8 float4 cols each)
#define EPS 1e-8f

// native clang vector type: accepted by __builtin_nontemporal_load
typedef float vf4 __attribute__((ext_vector_type(4)));

__device__ inline float wave_reduce_sum(float v) {
#pragma unroll
  for (int off = 1; off < 64; off <<= 1) v += __shfl_xor(v, off);
  return v;
}

__device__ inline float dot4(const float4& a, const float4& b) {
  return a.x * b.x + a.y * b.y + a.z * b.z + a.w * b.w;
}

__device__ inline float4 nt_load4(const float4* p) {
  vf4 v = __builtin_nontemporal_load((const vf4*)p);
  return make_float4(v.x, v.y, v.z, v.w);
}

// K_main: R9's proven structure (best: 31.97 us total), one change: z reads
// use nontemporal loads (nt cache policy) — probes whether the L3-hit path
// was the ~4.9 TB/s limiter. One block (4 waves) per b; each wave streams
// 16 p-rows as 8 pairs (depth-1 prefetch, ILP2 norm chains); LDS combine;
// an[b], Uv[b], diag[b]. Block 0 zeroes out[0].
__global__ __launch_bounds__(256) void k_main(const float* __restrict__ z,
                                              float* __restrict__ an,
                                              float* __restrict__ Uv,
                                              float* __restrict__ diag,
                                              float* __restrict__ out) {
  const int b = blockIdx.x;
  const int t = threadIdx.x;
  const int w = t >> 6;              // wave 0..3
  const int lane = t & 63;

  if (b == 0 && t == 0) out[0] = 0.f;  // boundary-visible to k_tail

  __shared__ float4 lds_zs[WAVES][D4];  // 16 KB
  __shared__ float4 lds_uu[WAVES][D4];  // 16 KB
  __shared__ float red[2 * WAVES];

  float4 zs[4], uu[4];
#pragma unroll
  for (int k = 0; k < 4; ++k) {
    zs[k] = make_float4(0.f, 0.f, 0.f, 0.f);
    uu[k] = make_float4(0.f, 0.f, 0.f, 0.f);
  }

  // wave w handles p = w*PC .. w*PC+PC-1, rows z[p][b][:]
  const size_t pstride = (size_t)B * D4;  // float4 stride between p's
  const float4* base = (const float4*)z + ((size_t)(w * PC) * B + b) * D4;

  float4 curA[4], curB[4];
#pragma unroll
  for (int k = 0; k < 4; ++k) {
    curA[k] = nt_load4(&base[k * 64 + lane]);
    curB[k] = nt_load4(&base[pstride + k * 64 + lane]);
  }

  for (int pr = 0; pr < PC / 2; ++pr) {
    float4 nxtA[4], nxtB[4];
    const bool more = (pr + 1 < PC / 2);
    if (more) {
      const float4* nA = base + (size_t)(2 * pr + 2) * pstride;
      const float4* nB = base + (size_t)(2 * pr + 3) * pstride;
#pragma unroll
      for (int k = 0; k < 4; ++k) {
        nxtA[k] = nt_load4(&nA[k * 64 + lane]);
        nxtB[k] = nt_load4(&nB[k * 64 + lane]);
      }
    }

    // two independent norm reductions, interleaved for ILP
    float ssA = 0.f, ssB = 0.f;
#pragma unroll
    for (int k = 0; k < 4; ++k) {
      ssA += dot4(curA[k], curA[k]);
      ssB += dot4(curB[k], curB[k]);
    }
#pragma unroll
    for (int off = 1; off < 64; off <<= 1) {
      ssA += __shfl_xor(ssA, off);
      ssB += __shfl_xor(ssB, off);
    }
    const float wA = 1.0f / fmaxf(sqrtf(ssA), EPS);
    const float wB = 1.0f / fmaxf(sqrtf(ssB), EPS);

#pragma unroll
    for (int k = 0; k < 4; ++k) {
      zs[k].x += curA[k].x + curB[k].x;
      zs[k].y += curA[k].y + curB[k].y;
      zs[k].z += curA[k].z + curB[k].z;
      zs[k].w += curA[k].w + curB[k].w;
      uu[k].x += wA * curA[k].x + wB * curB[k].x;
      uu[k].y += wA * curA[k].y + wB * curB[k].y;
      uu[k].z += wA * curA[k].z + wB * curB[k].z;
      uu[k].w += wA * curA[k].w + wB * curB[k].w;
    }
    if (more) {
#pragma unroll
      for (int k = 0; k < 4; ++k) {
        curA[k] = nxtA[k];
        curB[k] = nxtB[k];
      }
    }
  }

  // cross-wave combine: wave w's float4 index k*64+lane
#pragma unroll
  for (int k = 0; k < 4; ++k) {
    lds_zs[w][k * 64 + lane] = zs[k];
    lds_uu[w][k * 64 + lane] = uu[k];
  }
  __syncthreads();

  // thread t now owns float4 index t (d = 4t..4t+3)
  float4 zsum = make_float4(0.f, 0.f, 0.f, 0.f);
  float4 usum = make_float4(0.f, 0.f, 0.f, 0.f);
#pragma unroll
  for (int ww = 0; ww < WAVES; ++ww) {
    float4 a = lds_zs[ww][t];
    float4 u = lds_uu[ww][t];
    zsum.x += a.x; zsum.y += a.y; zsum.z += a.z; zsum.w += a.w;
    usum.x += u.x; usum.y += u.y; usum.z += u.z; usum.w += u.w;
  }

  // ||z_sum||^2 across the block, broadcast
  float ss = dot4(zsum, zsum);
  ss = wave_reduce_sum(ss);
  if (lane == 0) red[w] = ss;
  __syncthreads();
  ss = red[0] + red[1] + red[2] + red[3];

  // an = (z_sum/P)/max(||z_sum||/P, eps) = z_sum / max(||z_sum||, P*eps)
  const float inv = 1.0f / fmaxf(sqrtf(ss), (float)P * EPS);
  float4 a4 = make_float4(zsum.x * inv, zsum.y * inv, zsum.z * inv, zsum.w * inv);

  ((float4*)an)[(size_t)b * D4 + t] = a4;
  ((float4*)Uv)[(size_t)b * D4 + t] = usum;

  float dg = dot4(usum, a4);
  dg = wave_reduce_sum(dg);
  if (lane == 0) red[WAVES + w] = dg;
  __syncthreads();
  if (t == 0) diag[b] = red[WAVES] + red[WAVES + 1] + red[WAVES + 2] + red[WAVES + 3];
}

// K_tail: 32 blocks, d-split (R9-validated). Block blk owns float4-columns
// [blk*8, blk*8+8). Thread t: f4col = t&7, rowgroup = t>>3; accumulates
// S4/T4 over rows r = rowgroup + 32*i. Wave shfl + LDS combine complete the
// column sums; threads 0..7 dot them; block adds ONE scalar to out[0].
__global__ __launch_bounds__(256) void k_tail(const float* __restrict__ an,
                                              const float* __restrict__ Uv,
                                              const float* __restrict__ diag,
                                              float* __restrict__ out) {
  const int blk = blockIdx.x;
  const int t = threadIdx.x;
  const int w = t >> 6;
  const int lane = t & 63;
  const int f4c = blk * 8 + (t & 7);   // this thread's float4 column
  const int rg = t >> 3;               // rowgroup 0..31

  float4 S = make_float4(0.f, 0.f, 0.f, 0.f);
  float4 T = make_float4(0.f, 0.f, 0.f, 0.f);
#pragma unroll 4
  for (int i = 0; i < 16; ++i) {
    const size_t r = (size_t)rg + 32 * i;   // rows rg, rg+32, ..., rg+480
    float4 a = ((const float4*)an)[r * D4 + f4c];
    float4 u = ((const float4*)Uv)[r * D4 + f4c];
    S.x += a.x; S.y += a.y; S.z += a.z; S.w += a.w;
    T.x += u.x; T.y += u.y; T.z += u.z; T.w += u.w;
  }

  // reduce over the 8 rowgroups within this wave (lanes sharing lane&7)
#pragma unroll
  for (int off = 8; off < 64; off <<= 1) {
    S.x += __shfl_xor(S.x, off); S.y += __shfl_xor(S.y, off);
    S.z += __shfl_xor(S.z, off); S.w += __shfl_xor(S.w, off);
    T.x += __shfl_xor(T.x, off); T.y += __shfl_xor(T.y, off);
    T.z += __shfl_xor(T.z, off); T.w += __shfl_xor(T.w, off);
  }

  // combine the 4 waves via LDS
  __shared__ float4 ldsS[4][8], ldsT[4][8];
  if (lane < 8) {
    ldsS[w][lane] = S;
    ldsT[w][lane] = T;
  }
  __syncthreads();

  float dotp = 0.f;
  if (t < 8) {
    float4 Sf = ldsS[0][t], Tf = ldsT[0][t];
#pragma unroll
    for (int ww = 1; ww < 4; ++ww) {
      float4 s2 = ldsS[ww][t], t2 = ldsT[ww][t];
      Sf.x += s2.x; Sf.y += s2.y; Sf.z += s2.z; Sf.w += s2.w;
      Tf.x += t2.x; Tf.y += t2.y; Tf.z += t2.z; Tf.w += t2.w;
    }
    dotp = dot4(Sf, Tf);
  }
  // diag slice: 16 b's per block, lanes 16..31 of wave 0
  float dgp = 0.f;
  if (t >= 16 && t < 32) dgp = diag[blk * 16 + (t - 16)];

  if (w == 0) {
    float v = dotp - dgp;
    // sum lanes 0..31 (dot in 0..7, diag in 16..31): offsets 1,2,4,8,16
#pragma unroll
    for (int off = 1; off < 32; off <<= 1) v += __shfl_xor(v, off);
    if (t == 0) {
      const float count = 64.0f * 512.0f * 511.0f;  // P*B*(B-1)
      float contrib = v / count + (blk == 0 ? -1.0f : 0.0f);
      atomicAdd(out, contrib);
    }
  }
}

extern "C" void kernel_launch(void* const* d_in, const int* in_sizes, int n_in,
                              void* d_out, int out_size, void* d_ws, size_t ws_size,
                              hipStream_t stream) {
  const float* z = (const float*)d_in[0];  // z_list (P,B,D); d_in[1] unused

  float* ws = (float*)d_ws;
  float* an = ws;                                  // B*D (2 MB)
  float* Uv = an + (size_t)B * D;                  // B*D (2 MB)
  float* diag = Uv + (size_t)B * D;                // B

  k_main<<<B, 256, 0, stream>>>(z, an, Uv, diag, (float*)d_out);
  k_tail<<<TB, 256, 0, stream>>>(an, Uv, diag, (float*)d_out);
}